// Round 1
// baseline (1763.605 us; speedup 1.0000x reference)
//
#include <hip/hip_runtime.h>
#include <math.h>

constexpr int N  = 50000;
constexpr int E  = 800000;
constexpr int F1 = 128;
constexpr int F2 = 16;

// ---------- degree / norm ----------
__global__ void k_set_deg(float* deg) {
    int i = blockIdx.x * 256 + threadIdx.x;
    if (i < N) deg[i] = 1.0f;  // self-loop contributes 1 to every node's degree
}

__global__ void k_deg_acc(const int* __restrict__ col, float* deg) {
    int e = blockIdx.x * 256 + threadIdx.x;
    if (e < E) unsafeAtomicAdd(deg + col[e], 1.0f);
}

__global__ void k_dinv(float* deg) {
    int i = blockIdx.x * 256 + threadIdx.x;
    if (i < N) deg[i] = rsqrtf(deg[i]);  // deg >= 1 always
}

// ---------- GEMM1: h1 = x @ W1  [N,128]x[128,128] ----------
__global__ __launch_bounds__(256) void k_gemm1(const float* __restrict__ x,
                                               const float* __restrict__ W1,
                                               float* __restrict__ h1,
                                               int rows_per_block) {
    __shared__ float Wl[F1 * F1];   // 64 KB
    __shared__ float xs[2][F1];
    int t = threadIdx.x;
    for (int i = t; i < F1 * F1; i += 256) Wl[i] = W1[i];
    __syncthreads();

    int j = t & 127;
    int p = t >> 7;  // 0 or 1: which of the two rows this thread works on
    int row0 = blockIdx.x * rows_per_block;
    int row_end = min(row0 + rows_per_block, N);
    for (int r = row0; r < row_end; r += 2) {
        int rr = r + p;
        if (rr < N) xs[p][j] = x[(size_t)rr * F1 + j];
        __syncthreads();
        float acc = 0.f;
#pragma unroll 8
        for (int k = 0; k < F1; ++k)
            acc = fmaf(xs[p][k], Wl[k * F1 + j], acc);
        if (rr < N) h1[(size_t)rr * F1 + j] = acc;
        __syncthreads();
    }
}

// ---------- Scatter layer 1: agg1[col] += h1[row] * dinv[row]*dinv[col] ----------
// 32 threads per edge, float4 each (128 floats/edge)
__global__ __launch_bounds__(256) void k_scatter1(const int* __restrict__ row,
                                                  const int* __restrict__ col,
                                                  const float* __restrict__ dinv,
                                                  const float* __restrict__ h1,
                                                  float* __restrict__ agg1) {
    long long idx = (long long)blockIdx.x * 256 + threadIdx.x;
    int e = (int)(idx >> 5);
    int l = (int)(idx & 31);
    if (e >= E) return;
    int r = row[e], c = col[e];
    float w = dinv[r] * dinv[c];
    float4 v = ((const float4*)(h1 + (size_t)r * F1))[l];
    float* dst = agg1 + (size_t)c * F1 + l * 4;
    unsafeAtomicAdd(dst + 0, v.x * w);
    unsafeAtomicAdd(dst + 1, v.y * w);
    unsafeAtomicAdd(dst + 2, v.z * w);
    unsafeAtomicAdd(dst + 3, v.w * w);
}

// ---------- self-loop + bias + ReLU (writes in place over h1) ----------
__global__ void k_bias_relu(float* __restrict__ h1,
                            const float* __restrict__ agg1,
                            const float* __restrict__ dinv,
                            const float* __restrict__ b1) {
    long long idx = (long long)blockIdx.x * 256 + threadIdx.x;
    if (idx >= (long long)N * F1) return;
    int i = (int)(idx >> 7), j = (int)(idx & 127);
    float d = dinv[i];
    float v = agg1[idx] + d * d * h1[idx] + b1[j];
    h1[idx] = fmaxf(v, 0.f);
}

// ---------- GEMM2: h2 = h1relu @ W2  [N,128]x[128,16] ----------
__global__ __launch_bounds__(256) void k_gemm2(const float* __restrict__ h1,
                                               const float* __restrict__ W2,
                                               float* __restrict__ h2,
                                               int rows_per_block) {
    __shared__ float Wl[F1 * F2];      // 8 KB
    __shared__ float xs[16][F1 + 1];   // +1 pad: lanes with different p hit distinct banks
    int t = threadIdx.x;
    for (int i = t; i < F1 * F2; i += 256) Wl[i] = W2[i];
    __syncthreads();

    int j = t & 15;
    int p = t >> 4;  // 16 rows per iteration
    int row0 = blockIdx.x * rows_per_block;
    int row_end = min(row0 + rows_per_block, N);
    for (int r = row0; r < row_end; r += 16) {
        for (int i = t; i < 16 * F1; i += 256) {
            int rr = r + (i >> 7);
            xs[i >> 7][i & 127] = (rr < N) ? h1[(size_t)rr * F1 + (i & 127)] : 0.f;
        }
        __syncthreads();
        float acc = 0.f;
#pragma unroll 8
        for (int k = 0; k < F1; ++k)
            acc = fmaf(xs[p][k], Wl[k * F2 + j], acc);
        int rr = r + p;
        if (rr < N) h2[(size_t)rr * F2 + j] = acc;
        __syncthreads();
    }
}

// ---------- Scatter layer 2: 4 threads/edge, float4 each (16 floats/edge) ----------
__global__ __launch_bounds__(256) void k_scatter2(const int* __restrict__ row,
                                                  const int* __restrict__ col,
                                                  const float* __restrict__ dinv,
                                                  const float* __restrict__ h2,
                                                  float* __restrict__ agg2) {
    long long idx = (long long)blockIdx.x * 256 + threadIdx.x;
    int e = (int)(idx >> 2);
    int l = (int)(idx & 3);
    if (e >= E) return;
    int r = row[e], c = col[e];
    float w = dinv[r] * dinv[c];
    float4 v = ((const float4*)(h2 + (size_t)r * F2))[l];
    float* dst = agg2 + (size_t)c * F2 + l * 4;
    unsafeAtomicAdd(dst + 0, v.x * w);
    unsafeAtomicAdd(dst + 1, v.y * w);
    unsafeAtomicAdd(dst + 2, v.z * w);
    unsafeAtomicAdd(dst + 3, v.w * w);
}

// ---------- self-loop + bias + log_softmax ----------
__global__ void k_final(const float* __restrict__ agg2,
                        const float* __restrict__ h2,
                        const float* __restrict__ dinv,
                        const float* __restrict__ b2,
                        float* __restrict__ out) {
    int i = blockIdx.x * 256 + threadIdx.x;
    if (i >= N) return;
    float d = dinv[i];
    float d2 = d * d;
    float v[F2];
    float mx = -1e30f;
#pragma unroll
    for (int j = 0; j < F2; ++j) {
        v[j] = agg2[(size_t)i * F2 + j] + d2 * h2[(size_t)i * F2 + j] + b2[j];
        mx = fmaxf(mx, v[j]);
    }
    float s = 0.f;
#pragma unroll
    for (int j = 0; j < F2; ++j) s += expf(v[j] - mx);
    float lse = mx + logf(s);
#pragma unroll
    for (int j = 0; j < F2; ++j) out[(size_t)i * F2 + j] = v[j] - lse;
}

extern "C" void kernel_launch(void* const* d_in, const int* in_sizes, int n_in,
                              void* d_out, int out_size, void* d_ws, size_t ws_size,
                              hipStream_t stream) {
    const float* x  = (const float*)d_in[0];
    const int*   ei = (const int*)d_in[1];   // [2, E], int32 per harness convention
    const float* W1 = (const float*)d_in[2];
    const float* b1 = (const float*)d_in[3];
    const float* W2 = (const float*)d_in[4];
    const float* b2 = (const float*)d_in[5];
    const int* row = ei;
    const int* col = ei + E;

    float* wsf  = (float*)d_ws;
    float* deg  = wsf;                          // N (becomes dinv in place)
    float* h1   = deg + N;                      // N*128
    float* agg1 = h1 + (size_t)N * F1;          // N*128
    float* h2   = agg1 + (size_t)N * F1;        // N*16
    float* agg2 = h2 + (size_t)N * F2;          // N*16

    hipMemsetAsync(agg1, 0, (size_t)N * F1 * sizeof(float), stream);
    hipMemsetAsync(agg2, 0, (size_t)N * F2 * sizeof(float), stream);

    k_set_deg<<<(N + 255) / 256, 256, 0, stream>>>(deg);
    k_deg_acc<<<(E + 255) / 256, 256, 0, stream>>>(col, deg);
    k_dinv<<<(N + 255) / 256, 256, 0, stream>>>(deg);

    k_gemm1<<<(N + 49) / 50, 256, 0, stream>>>(x, W1, h1, 50);

    k_scatter1<<<((long long)E * 32 + 255) / 256, 256, 0, stream>>>(row, col, deg, h1, agg1);
    k_bias_relu<<<((long long)N * F1 + 255) / 256, 256, 0, stream>>>(h1, agg1, deg, b1);

    k_gemm2<<<(N + 63) / 64, 256, 0, stream>>>(h1, W2, h2, 64);

    k_scatter2<<<((long long)E * 4 + 255) / 256, 256, 0, stream>>>(row, col, deg, h2, agg2);
    k_final<<<(N + 255) / 256, 256, 0, stream>>>(agg2, h2, deg, b2, (float*)d_out);
}

// Round 2
// 478.041 us; speedup vs baseline: 3.6892x; 3.6892x over previous
//
#include <hip/hip_runtime.h>
#include <math.h>

constexpr int N  = 50000;
constexpr int E  = 800000;
constexpr int F1 = 128;
constexpr int F2 = 16;

// ---------- CSR build: counts per destination ----------
__global__ void k_count(const int* __restrict__ col, int* __restrict__ counts) {
    int e = blockIdx.x * 256 + threadIdx.x;
    if (e < E) atomicAdd(counts + col[e], 1);
}

// dinv[i] = rsqrt(counts[i] + 1)   (self-loop adds 1)
__global__ void k_dinv(const int* __restrict__ counts, float* __restrict__ dinv) {
    int i = blockIdx.x * 256 + threadIdx.x;
    if (i < N) dinv[i] = rsqrtf((float)counts[i] + 1.0f);
}

// single-block exclusive scan over counts[N] -> offsets[N+1]
__global__ __launch_bounds__(1024) void k_scan(const int* __restrict__ counts,
                                               int* __restrict__ offsets) {
    __shared__ int tmp[1024];
    __shared__ int carry_s;
    int t = threadIdx.x;
    if (t == 0) carry_s = 0;
    __syncthreads();
    for (int base = 0; base < N; base += 1024) {
        int v = (base + t < N) ? counts[base + t] : 0;
        tmp[t] = v;
        __syncthreads();
#pragma unroll
        for (int d = 1; d < 1024; d <<= 1) {
            int add = (t >= d) ? tmp[t - d] : 0;
            __syncthreads();
            tmp[t] += add;
            __syncthreads();
        }
        int incl = tmp[t];
        int chunk_total = tmp[1023];
        int c = carry_s;
        if (base + t < N) offsets[base + t] = c + incl - v;  // exclusive
        __syncthreads();
        if (t == 0) carry_s = c + chunk_total;
        __syncthreads();
    }
    if (t == 0) offsets[N] = carry_s;  // == E
}

// fill buckets: csr_src[offsets[c] + pos] = row  (order within bucket irrelevant)
__global__ void k_bucket(const int* __restrict__ row, const int* __restrict__ col,
                         const int* __restrict__ offsets, int* __restrict__ cursor,
                         int* __restrict__ csr_src) {
    int e = blockIdx.x * 256 + threadIdx.x;
    if (e >= E) return;
    int c = col[e];
    int pos = atomicAdd(cursor + c, 1);
    csr_src[offsets[c] + pos] = row[e];
}

// ---------- GEMM1: h1 = x @ W1  [N,128]x[128,128] ----------
__global__ __launch_bounds__(256) void k_gemm1(const float* __restrict__ x,
                                               const float* __restrict__ W1,
                                               float* __restrict__ h1,
                                               int rows_per_block) {
    __shared__ float Wl[F1 * F1];   // 64 KB
    __shared__ float xs[2][F1];
    int t = threadIdx.x;
    for (int i = t; i < F1 * F1; i += 256) Wl[i] = W1[i];
    __syncthreads();

    int j = t & 127;
    int p = t >> 7;
    int row0 = blockIdx.x * rows_per_block;
    int row_end = min(row0 + rows_per_block, N);
    for (int r = row0; r < row_end; r += 2) {
        int rr = r + p;
        if (rr < N) xs[p][j] = x[(size_t)rr * F1 + j];
        __syncthreads();
        float acc = 0.f;
#pragma unroll 8
        for (int k = 0; k < F1; ++k)
            acc = fmaf(xs[p][k], Wl[k * F1 + j], acc);
        if (rr < N) h1[(size_t)rr * F1 + j] = acc;
        __syncthreads();
    }
}

// ---------- Gather layer 1 + self-loop + bias + ReLU ----------
// one 64-lane wave per destination node; float2 per lane (128 floats)
__global__ __launch_bounds__(256) void k_gather1(const float* __restrict__ h1,
                                                 const int* __restrict__ offsets,
                                                 const int* __restrict__ csr_src,
                                                 const float* __restrict__ dinv,
                                                 const float* __restrict__ b1,
                                                 float* __restrict__ h1r) {
    int wave = (blockIdx.x * 256 + threadIdx.x) >> 6;
    int lane = threadIdx.x & 63;
    if (wave >= N) return;
    int c = wave;
    int s = offsets[c], t_end = offsets[c + 1];
    float ax = 0.f, ay = 0.f;
    for (int k = s; k < t_end; ++k) {
        int r = csr_src[k];          // wave-uniform (broadcast load)
        float w = dinv[r];
        float2 v = ((const float2*)(h1 + (size_t)r * F1))[lane];
        ax = fmaf(v.x, w, ax);
        ay = fmaf(v.y, w, ay);
    }
    float dc = dinv[c];
    float2 self = ((const float2*)(h1 + (size_t)c * F1))[lane];
    float2 bb = ((const float2*)b1)[lane];
    float o0 = fmaf(ax, dc, fmaf(dc * dc, self.x, bb.x));
    float o1 = fmaf(ay, dc, fmaf(dc * dc, self.y, bb.y));
    float2 out;
    out.x = fmaxf(o0, 0.f);
    out.y = fmaxf(o1, 0.f);
    ((float2*)(h1r + (size_t)c * F1))[lane] = out;
}

// ---------- GEMM2: h2 = h1r @ W2  [N,128]x[128,16] ----------
__global__ __launch_bounds__(256) void k_gemm2(const float* __restrict__ h1,
                                               const float* __restrict__ W2,
                                               float* __restrict__ h2,
                                               int rows_per_block) {
    __shared__ float Wl[F1 * F2];      // 8 KB
    __shared__ float xs[16][F1 + 1];
    int t = threadIdx.x;
    for (int i = t; i < F1 * F2; i += 256) Wl[i] = W2[i];
    __syncthreads();

    int j = t & 15;
    int p = t >> 4;
    int row0 = blockIdx.x * rows_per_block;
    int row_end = min(row0 + rows_per_block, N);
    for (int r = row0; r < row_end; r += 16) {
        for (int i = t; i < 16 * F1; i += 256) {
            int rr = r + (i >> 7);
            xs[i >> 7][i & 127] = (rr < N) ? h1[(size_t)rr * F1 + (i & 127)] : 0.f;
        }
        __syncthreads();
        float acc = 0.f;
#pragma unroll 8
        for (int k = 0; k < F1; ++k)
            acc = fmaf(xs[p][k], Wl[k * F2 + j], acc);
        int rr = r + p;
        if (rr < N) h2[(size_t)rr * F2 + j] = acc;
        __syncthreads();
    }
}

// ---------- Gather layer 2 + self-loop + bias + log_softmax ----------
// 16 lanes per node (4 nodes per wave), one feature per lane
__global__ __launch_bounds__(256) void k_gather2(const float* __restrict__ h2,
                                                 const int* __restrict__ offsets,
                                                 const int* __restrict__ csr_src,
                                                 const float* __restrict__ dinv,
                                                 const float* __restrict__ b2,
                                                 float* __restrict__ out) {
    int idx = blockIdx.x * 256 + threadIdx.x;
    int node = idx >> 4;
    int j = idx & 15;
    if (node >= N) return;
    int s = offsets[node], t_end = offsets[node + 1];
    float acc = 0.f;
    for (int k = s; k < t_end; ++k) {
        int r = csr_src[k];
        acc = fmaf(dinv[r], h2[(size_t)r * F2 + j], acc);
    }
    float dc = dinv[node];
    float v = fmaf(acc, dc, fmaf(dc * dc, h2[(size_t)node * F2 + j], b2[j]));
    // 16-lane log-softmax (xor masks stay within the 16-lane group)
    float mx = v;
#pragma unroll
    for (int m = 1; m < 16; m <<= 1) mx = fmaxf(mx, __shfl_xor(mx, m));
    float ex = expf(v - mx);
    float sm = ex;
#pragma unroll
    for (int m = 1; m < 16; m <<= 1) sm += __shfl_xor(sm, m);
    out[(size_t)node * F2 + j] = v - mx - logf(sm);
}

extern "C" void kernel_launch(void* const* d_in, const int* in_sizes, int n_in,
                              void* d_out, int out_size, void* d_ws, size_t ws_size,
                              hipStream_t stream) {
    const float* x  = (const float*)d_in[0];
    const int*   ei = (const int*)d_in[1];   // [2, E] int32
    const float* W1 = (const float*)d_in[2];
    const float* b1 = (const float*)d_in[3];
    const float* W2 = (const float*)d_in[4];
    const float* b2 = (const float*)d_in[5];
    const int* row = ei;
    const int* col = ei + E;

    char* ws = (char*)d_ws;
    int*   counts  = (int*)ws;                 ws += (size_t)N * 4;
    int*   cursor  = (int*)ws;                 ws += (size_t)N * 4;
    int*   offsets = (int*)ws;                 ws += (size_t)(N + 1) * 4;
    int*   csr_src = (int*)ws;                 ws += (size_t)E * 4;
    float* dinv    = (float*)ws;               ws += (size_t)N * 4;
    float* h1      = (float*)ws;               ws += (size_t)N * F1 * 4;
    float* h1r     = (float*)ws;               ws += (size_t)N * F1 * 4;
    float* h2      = (float*)ws;               ws += (size_t)N * F2 * 4;

    // zero counts + cursor (adjacent)
    hipMemsetAsync(counts, 0, (size_t)N * 2 * 4, stream);

    // CSR build + norm
    k_count<<<(E + 255) / 256, 256, 0, stream>>>(col, counts);
    k_dinv<<<(N + 255) / 256, 256, 0, stream>>>(counts, dinv);
    k_scan<<<1, 1024, 0, stream>>>(counts, offsets);
    k_bucket<<<(E + 255) / 256, 256, 0, stream>>>(row, col, offsets, cursor, csr_src);

    // layer 1
    k_gemm1<<<(N + 49) / 50, 256, 0, stream>>>(x, W1, h1, 50);
    k_gather1<<<((size_t)N * 64 + 255) / 256, 256, 0, stream>>>(h1, offsets, csr_src, dinv, b1, h1r);

    // layer 2
    k_gemm2<<<(N + 63) / 64, 256, 0, stream>>>(h1r, W2, h2, 64);
    k_gather2<<<((size_t)N * 16 + 255) / 256, 256, 0, stream>>>(h2, offsets, csr_src, dinv, b2,
                                                                (float*)d_out);
}

// Round 3
// 345.664 us; speedup vs baseline: 5.1021x; 1.3830x over previous
//
#include <hip/hip_runtime.h>
#include <math.h>

constexpr int N  = 50000;
constexpr int E  = 800000;
constexpr int F1 = 128;
constexpr int F2 = 16;

typedef unsigned short ushort_t;
typedef __bf16 bf16x8 __attribute__((ext_vector_type(8)));
typedef float  f32x4  __attribute__((ext_vector_type(4)));

// ---------- CSR build: counts per destination ----------
__global__ void k_count(const int* __restrict__ col, int* __restrict__ counts) {
    int e = blockIdx.x * 256 + threadIdx.x;
    if (e < E) atomicAdd(counts + col[e], 1);
}

__global__ void k_dinv(const int* __restrict__ counts, float* __restrict__ dinv) {
    int i = blockIdx.x * 256 + threadIdx.x;
    if (i < N) dinv[i] = rsqrtf((float)counts[i] + 1.0f);
}

// single-block exclusive scan, wave-shuffle based (4 barriers/chunk)
__global__ __launch_bounds__(1024) void k_scan(const int* __restrict__ counts,
                                               int* __restrict__ offsets) {
    __shared__ int woff[16];
    __shared__ int tot_s;
    __shared__ int carry_s;
    int t = threadIdx.x, lane = t & 63, wid = t >> 6;
    if (t == 0) carry_s = 0;
    __syncthreads();
    for (int base = 0; base < N; base += 1024) {
        int v = (base + t < N) ? counts[base + t] : 0;
        int incl = v;
#pragma unroll
        for (int d = 1; d < 64; d <<= 1) {
            int u = __shfl_up(incl, d, 64);
            if (lane >= d) incl += u;
        }
        if (lane == 63) woff[wid] = incl;
        __syncthreads();
        if (wid == 0) {
            int ws = (lane < 16) ? woff[lane] : 0;
            int wincl = ws;
#pragma unroll
            for (int d = 1; d < 16; d <<= 1) {
                int u = __shfl_up(wincl, d, 64);
                if (lane >= d) wincl += u;
            }
            if (lane < 16) woff[lane] = wincl - ws;  // exclusive
            if (lane == 15) tot_s = wincl;
        }
        __syncthreads();
        int c0 = carry_s;
        if (base + t < N) offsets[base + t] = c0 + woff[wid] + incl - v;
        __syncthreads();
        if (t == 0) carry_s = c0 + tot_s;
        __syncthreads();
    }
    if (t == 0) offsets[N] = carry_s;  // == E
}

__global__ void k_bucket(const int* __restrict__ row, const int* __restrict__ col,
                         const int* __restrict__ offsets, int* __restrict__ cursor,
                         int* __restrict__ csr_src) {
    int e = blockIdx.x * 256 + threadIdx.x;
    if (e >= E) return;
    int c = col[e];
    int pos = atomicAdd(cursor + c, 1);
    csr_src[offsets[c] + pos] = row[e];
}

// ---------- W1 -> bf16, transposed: Wt[n][k] ----------
__global__ void k_prep_w(const float* __restrict__ W1, ushort_t* __restrict__ Wt) {
    int i = blockIdx.x * 256 + threadIdx.x;
    if (i < F1 * F1) {
        int k = i >> 7, n = i & 127;
        __bf16 h = (__bf16)W1[i];
        Wt[n * F1 + k] = *(ushort_t*)&h;
    }
}

// ---------- GEMM1 (MFMA bf16): h1b = bf16(x @ W1)  [N,128]x[128,128] ----------
// block = 256 (4 waves), 64 rows/block; W in LDS padded stride 136 (2-way conflicts only)
__global__ __launch_bounds__(256) void k_gemm1_mfma(const float* __restrict__ x,
                                                    const ushort_t* __restrict__ Wt,
                                                    ushort_t* __restrict__ h1b) {
    __shared__ ushort_t Wl[F1 * 136];
    int t = threadIdx.x;
    for (int i = t; i < F1 * 16; i += 256) {  // 16 B chunks: 16 per row
        int n = i >> 4, c = (i & 15) * 8;
        *(int4*)&Wl[n * 136 + c] = *(const int4*)&Wt[n * F1 + c];
    }
    __syncthreads();

    int lane = t & 63, wv = t >> 6;
    int quad = lane >> 4, l15 = lane & 15;
    int arow = blockIdx.x * 64 + wv * 16 + l15;
    int rclamp = min(arow, N - 1);
    f32x4 acc[8] = {};

#pragma unroll
    for (int kk = 0; kk < 4; ++kk) {
        int k0 = kk * 32 + quad * 8;
        const float* xp = x + (size_t)rclamp * F1 + k0;
        float4 u0 = *(const float4*)xp;
        float4 u1 = *(const float4*)(xp + 4);
        bf16x8 a;
        a[0] = (__bf16)u0.x; a[1] = (__bf16)u0.y; a[2] = (__bf16)u0.z; a[3] = (__bf16)u0.w;
        a[4] = (__bf16)u1.x; a[5] = (__bf16)u1.y; a[6] = (__bf16)u1.z; a[7] = (__bf16)u1.w;
#pragma unroll
        for (int ct = 0; ct < 8; ++ct) {
            bf16x8 b = *(const bf16x8*)&Wl[(ct * 16 + l15) * 136 + k0];
            acc[ct] = __builtin_amdgcn_mfma_f32_16x16x32_bf16(a, b, acc[ct], 0, 0, 0);
        }
    }

    // epilogue: C/D layout col=lane&15, row=quad*4+reg -> store bf16
    int orow0 = blockIdx.x * 64 + wv * 16 + quad * 4;
#pragma unroll
    for (int ct = 0; ct < 8; ++ct) {
#pragma unroll
        for (int r = 0; r < 4; ++r) {
            int orow = orow0 + r;
            if (orow < N) {
                __bf16 h = (__bf16)acc[ct][r];
                h1b[(size_t)orow * F1 + ct * 16 + l15] = *(ushort_t*)&h;
            }
        }
    }
}

// ---------- Gather layer 1 (bf16 in, fp32 out) + self-loop + bias + ReLU ----------
// one 64-lane wave per node; each lane handles 2 features via one dword (bf16x2)
__global__ __launch_bounds__(256) void k_gather1(const ushort_t* __restrict__ h1b,
                                                 const int* __restrict__ offsets,
                                                 const int* __restrict__ csr_src,
                                                 const float* __restrict__ dinv,
                                                 const float* __restrict__ b1,
                                                 float* __restrict__ h1r) {
    int wave = (blockIdx.x * 256 + threadIdx.x) >> 6;
    int lane = threadIdx.x & 63;
    if (wave >= N) return;
    int c = wave;
    int s = offsets[c], t_end = offsets[c + 1];
    float ax = 0.f, ay = 0.f;
    for (int k = s; k < t_end; ++k) {
        int r = csr_src[k];  // wave-uniform
        float w = dinv[r];
        unsigned int u = ((const unsigned int*)(h1b + (size_t)r * F1))[lane];
        float lo = __uint_as_float(u << 16);
        float hi = __uint_as_float(u & 0xffff0000u);
        ax = fmaf(lo, w, ax);
        ay = fmaf(hi, w, ay);
    }
    float dc = dinv[c];
    unsigned int us = ((const unsigned int*)(h1b + (size_t)c * F1))[lane];
    float slo = __uint_as_float(us << 16);
    float shi = __uint_as_float(us & 0xffff0000u);
    float2 bb = ((const float2*)b1)[lane];
    float o0 = fmaf(ax, dc, fmaf(dc * dc, slo, bb.x));
    float o1 = fmaf(ay, dc, fmaf(dc * dc, shi, bb.y));
    float2 out;
    out.x = fmaxf(o0, 0.f);
    out.y = fmaxf(o1, 0.f);
    ((float2*)(h1r + (size_t)c * F1))[lane] = out;
}

// ---------- GEMM2: h2 = h1r @ W2  [N,128]x[128,16] (fp32) ----------
__global__ __launch_bounds__(256) void k_gemm2(const float* __restrict__ h1,
                                               const float* __restrict__ W2,
                                               float* __restrict__ h2,
                                               int rows_per_block) {
    __shared__ float Wl[F1 * F2];
    __shared__ float xs[16][F1 + 1];
    int t = threadIdx.x;
    for (int i = t; i < F1 * F2; i += 256) Wl[i] = W2[i];
    __syncthreads();

    int j = t & 15;
    int p = t >> 4;
    int row0 = blockIdx.x * rows_per_block;
    int row_end = min(row0 + rows_per_block, N);
    for (int r = row0; r < row_end; r += 16) {
        for (int i = t; i < 16 * F1; i += 256) {
            int rr = r + (i >> 7);
            xs[i >> 7][i & 127] = (rr < N) ? h1[(size_t)rr * F1 + (i & 127)] : 0.f;
        }
        __syncthreads();
        float acc = 0.f;
#pragma unroll 8
        for (int k = 0; k < F1; ++k)
            acc = fmaf(xs[p][k], Wl[k * F2 + j], acc);
        int rr = r + p;
        if (rr < N) h2[(size_t)rr * F2 + j] = acc;
        __syncthreads();
    }
}

// ---------- Gather layer 2 + self-loop + bias + log_softmax ----------
__global__ __launch_bounds__(256) void k_gather2(const float* __restrict__ h2,
                                                 const int* __restrict__ offsets,
                                                 const int* __restrict__ csr_src,
                                                 const float* __restrict__ dinv,
                                                 const float* __restrict__ b2,
                                                 float* __restrict__ out) {
    int idx = blockIdx.x * 256 + threadIdx.x;
    int node = idx >> 4;
    int j = idx & 15;
    if (node >= N) return;
    int s = offsets[node], t_end = offsets[node + 1];
    float acc = 0.f;
    for (int k = s; k < t_end; ++k) {
        int r = csr_src[k];
        acc = fmaf(dinv[r], h2[(size_t)r * F2 + j], acc);
    }
    float dc = dinv[node];
    float v = fmaf(acc, dc, fmaf(dc * dc, h2[(size_t)node * F2 + j], b2[j]));
    float mx = v;
#pragma unroll
    for (int m = 1; m < 16; m <<= 1) mx = fmaxf(mx, __shfl_xor(mx, m));
    float ex = expf(v - mx);
    float sm = ex;
#pragma unroll
    for (int m = 1; m < 16; m <<= 1) sm += __shfl_xor(sm, m);
    out[(size_t)node * F2 + j] = v - mx - logf(sm);
}

extern "C" void kernel_launch(void* const* d_in, const int* in_sizes, int n_in,
                              void* d_out, int out_size, void* d_ws, size_t ws_size,
                              hipStream_t stream) {
    const float* x  = (const float*)d_in[0];
    const int*   ei = (const int*)d_in[1];   // [2, E] int32
    const float* W1 = (const float*)d_in[2];
    const float* b1 = (const float*)d_in[3];
    const float* W2 = (const float*)d_in[4];
    const float* b2 = (const float*)d_in[5];
    const int* row = ei;
    const int* col = ei + E;

    char* ws = (char*)d_ws;
    int*      counts  = (int*)ws;      ws += (size_t)N * 4;
    int*      cursor  = (int*)ws;      ws += (size_t)N * 4;
    int*      offsets = (int*)ws;      ws += (size_t)(N + 1) * 4;
    int*      csr_src = (int*)ws;      ws += (size_t)E * 4;
    float*    dinv    = (float*)ws;    ws += (size_t)N * 4;
    ushort_t* Wt      = (ushort_t*)ws; ws += (size_t)F1 * F1 * 2;
    ushort_t* h1b     = (ushort_t*)ws; ws += (size_t)N * F1 * 2;
    float*    h1r     = (float*)ws;    ws += (size_t)N * F1 * 4;
    float*    h2      = (float*)ws;    ws += (size_t)N * F2 * 4;

    hipMemsetAsync(counts, 0, (size_t)N * 2 * 4, stream);  // counts + cursor

    // CSR build + norm (independent of GEMM1 — scheduler may overlap)
    k_count<<<(E + 255) / 256, 256, 0, stream>>>(col, counts);
    k_dinv<<<(N + 255) / 256, 256, 0, stream>>>(counts, dinv);
    k_scan<<<1, 1024, 0, stream>>>(counts, offsets);
    k_bucket<<<(E + 255) / 256, 256, 0, stream>>>(row, col, offsets, cursor, csr_src);

    // layer 1
    k_prep_w<<<(F1 * F1 + 255) / 256, 256, 0, stream>>>(W1, Wt);
    k_gemm1_mfma<<<(N + 63) / 64, 256, 0, stream>>>(x, Wt, h1b);
    k_gather1<<<((size_t)N * 64 + 255) / 256, 256, 0, stream>>>(h1b, offsets, csr_src, dinv, b1, h1r);

    // layer 2 (fp32 throughout)
    k_gemm2<<<(N + 63) / 64, 256, 0, stream>>>(h1r, W2, h2, 64);
    k_gather2<<<((size_t)N * 16 + 255) / 256, 256, 0, stream>>>(h2, offsets, csr_src, dinv, b2,
                                                                (float*)d_out);
}

// Round 4
// 271.475 us; speedup vs baseline: 6.4964x; 1.2733x over previous
//
#include <hip/hip_runtime.h>
#include <math.h>

constexpr int N  = 50000;
constexpr int E  = 800000;
constexpr int F1 = 128;
constexpr int F2 = 16;

typedef unsigned short ushort_t;
typedef __bf16 bf16x8 __attribute__((ext_vector_type(8)));
typedef float  f32x4  __attribute__((ext_vector_type(4)));

static __device__ __forceinline__ float blo(unsigned u) { return __uint_as_float(u << 16); }
static __device__ __forceinline__ float bhi(unsigned u) { return __uint_as_float(u & 0xffff0000u); }
static __device__ __forceinline__ ushort_t to_bf(float f) { __bf16 h = (__bf16)f; return *(ushort_t*)&h; }

// ---------- CSR build ----------
__global__ void k_count(const int* __restrict__ col, int* __restrict__ counts) {
    int e = blockIdx.x * 256 + threadIdx.x;
    if (e < E) atomicAdd(counts + col[e], 1);
}

__global__ void k_dinv(const int* __restrict__ counts, float* __restrict__ dinv) {
    int i = blockIdx.x * 256 + threadIdx.x;
    if (i < N) dinv[i] = rsqrtf((float)counts[i] + 1.0f);
}

// single-block exclusive scan, wave-shuffle based
__global__ __launch_bounds__(1024) void k_scan(const int* __restrict__ counts,
                                               int* __restrict__ offsets) {
    __shared__ int woff[16];
    __shared__ int tot_s;
    __shared__ int carry_s;
    int t = threadIdx.x, lane = t & 63, wid = t >> 6;
    if (t == 0) carry_s = 0;
    __syncthreads();
    for (int base = 0; base < N; base += 1024) {
        int v = (base + t < N) ? counts[base + t] : 0;
        int incl = v;
#pragma unroll
        for (int d = 1; d < 64; d <<= 1) {
            int u = __shfl_up(incl, d, 64);
            if (lane >= d) incl += u;
        }
        if (lane == 63) woff[wid] = incl;
        __syncthreads();
        if (wid == 0) {
            int ws = (lane < 16) ? woff[lane] : 0;
            int wincl = ws;
#pragma unroll
            for (int d = 1; d < 16; d <<= 1) {
                int u = __shfl_up(wincl, d, 64);
                if (lane >= d) wincl += u;
            }
            if (lane < 16) woff[lane] = wincl - ws;
            if (lane == 15) tot_s = wincl;
        }
        __syncthreads();
        int c0 = carry_s;
        if (base + t < N) offsets[base + t] = c0 + woff[wid] + incl - v;
        __syncthreads();
        if (t == 0) carry_s = c0 + tot_s;
        __syncthreads();
    }
    if (t == 0) offsets[N] = carry_s;
}

__global__ void k_bucket(const int* __restrict__ row, const int* __restrict__ col,
                         const int* __restrict__ offsets, int* __restrict__ cursor,
                         int* __restrict__ csr_src) {
    int e = blockIdx.x * 256 + threadIdx.x;
    if (e >= E) return;
    int c = col[e];
    int pos = atomicAdd(cursor + c, 1);
    csr_src[offsets[c] + pos] = row[e];
}

// ---------- W1,W2 -> bf16 transposed ----------
__global__ void k_prep_w(const float* __restrict__ W1, const float* __restrict__ W2,
                         ushort_t* __restrict__ W1t, ushort_t* __restrict__ W2t) {
    int i = blockIdx.x * 256 + threadIdx.x;
    if (i < F1 * F1) {
        int k = i >> 7, n = i & 127;
        W1t[n * F1 + k] = to_bf(W1[i]);
    }
    if (i < F1 * F2) {
        int k = i >> 4, n = i & 15;
        W2t[n * F1 + k] = to_bf(W2[i]);
    }
}

// ---------- GEMM1 (MFMA bf16): h1s = bf16(dinv[r] * (x @ W1)[r])  ----------
__global__ __launch_bounds__(256) void k_gemm1_mfma(const float* __restrict__ x,
                                                    const ushort_t* __restrict__ W1t,
                                                    const float* __restrict__ dinv,
                                                    ushort_t* __restrict__ h1s) {
    __shared__ ushort_t Wl[F1 * 136];
    int t = threadIdx.x;
    for (int i = t; i < F1 * 16; i += 256) {
        int n = i >> 4, c = (i & 15) * 8;
        *(int4*)&Wl[n * 136 + c] = *(const int4*)&W1t[n * F1 + c];
    }
    __syncthreads();

    int lane = t & 63, wv = t >> 6;
    int quad = lane >> 4, l15 = lane & 15;
    int arow = blockIdx.x * 64 + wv * 16 + l15;
    int rclamp = min(arow, N - 1);
    f32x4 acc[8] = {};

#pragma unroll
    for (int kk = 0; kk < 4; ++kk) {
        int k0 = kk * 32 + quad * 8;
        const float* xp = x + (size_t)rclamp * F1 + k0;
        float4 u0 = *(const float4*)xp;
        float4 u1 = *(const float4*)(xp + 4);
        bf16x8 a;
        a[0] = (__bf16)u0.x; a[1] = (__bf16)u0.y; a[2] = (__bf16)u0.z; a[3] = (__bf16)u0.w;
        a[4] = (__bf16)u1.x; a[5] = (__bf16)u1.y; a[6] = (__bf16)u1.z; a[7] = (__bf16)u1.w;
#pragma unroll
        for (int ct = 0; ct < 8; ++ct) {
            bf16x8 b = *(const bf16x8*)&Wl[(ct * 16 + l15) * 136 + k0];
            acc[ct] = __builtin_amdgcn_mfma_f32_16x16x32_bf16(a, b, acc[ct], 0, 0, 0);
        }
    }

    int orow0 = blockIdx.x * 64 + wv * 16 + quad * 4;
#pragma unroll
    for (int r = 0; r < 4; ++r) {
        int orow = orow0 + r;
        if (orow < N) {
            float d = dinv[orow];
#pragma unroll
            for (int ct = 0; ct < 8; ++ct)
                h1s[(size_t)orow * F1 + ct * 16 + l15] = to_bf(acc[ct][r] * d);
        }
    }
}

// ---------- Gather 1: h1r = relu(dinv_c * (sum h1s[r] + h1s[c]) + b1), bf16 out ----------
// one wave per node, bf16x2 per lane, x4 unrolled for MLP
__global__ __launch_bounds__(256) void k_gather1(const ushort_t* __restrict__ h1s,
                                                 const int* __restrict__ offsets,
                                                 const int* __restrict__ csr_src,
                                                 const float* __restrict__ dinv,
                                                 const float* __restrict__ b1,
                                                 ushort_t* __restrict__ h1rb) {
    int c = (blockIdx.x * 256 + threadIdx.x) >> 6;
    int lane = threadIdx.x & 63;
    if (c >= N) return;
    int s = offsets[c], e = offsets[c + 1];
    float ax = 0.f, ay = 0.f;
    int k = s;
    for (; k + 4 <= e; k += 4) {
        int r0 = csr_src[k], r1 = csr_src[k + 1], r2 = csr_src[k + 2], r3 = csr_src[k + 3];
        unsigned u0 = ((const unsigned*)(h1s + (size_t)r0 * F1))[lane];
        unsigned u1 = ((const unsigned*)(h1s + (size_t)r1 * F1))[lane];
        unsigned u2 = ((const unsigned*)(h1s + (size_t)r2 * F1))[lane];
        unsigned u3 = ((const unsigned*)(h1s + (size_t)r3 * F1))[lane];
        ax += (blo(u0) + blo(u1)) + (blo(u2) + blo(u3));
        ay += (bhi(u0) + bhi(u1)) + (bhi(u2) + bhi(u3));
    }
    for (; k < e; ++k) {
        unsigned u = ((const unsigned*)(h1s + (size_t)csr_src[k] * F1))[lane];
        ax += blo(u);
        ay += bhi(u);
    }
    unsigned us = ((const unsigned*)(h1s + (size_t)c * F1))[lane];
    ax += blo(us);
    ay += bhi(us);
    float dc = dinv[c];
    float2 bb = ((const float2*)b1)[lane];
    float o0 = fmaxf(fmaf(dc, ax, bb.x), 0.f);
    float o1 = fmaxf(fmaf(dc, ay, bb.y), 0.f);
    unsigned pw = (unsigned)to_bf(o0) | ((unsigned)to_bf(o1) << 16);
    ((unsigned*)(h1rb + (size_t)c * F1))[lane] = pw;
}

// ---------- GEMM2 (MFMA bf16): h2s = bf16(dinv[r] * (h1r @ W2)[r]) ----------
__global__ __launch_bounds__(256) void k_gemm2_mfma(const ushort_t* __restrict__ h1rb,
                                                    const ushort_t* __restrict__ W2t,
                                                    const float* __restrict__ dinv,
                                                    ushort_t* __restrict__ h2s) {
    int t = threadIdx.x, lane = t & 63, wv = t >> 6;
    int quad = lane >> 4, l15 = lane & 15;
    int arow = blockIdx.x * 64 + wv * 16 + l15;
    int rclamp = min(arow, N - 1);
    f32x4 acc = {};
#pragma unroll
    for (int kk = 0; kk < 4; ++kk) {
        int k0 = kk * 32 + quad * 8;
        bf16x8 a = *(const bf16x8*)(h1rb + (size_t)rclamp * F1 + k0);
        bf16x8 b = *(const bf16x8*)(W2t + l15 * F1 + k0);  // 4 KB, L1-resident
        acc = __builtin_amdgcn_mfma_f32_16x16x32_bf16(a, b, acc, 0, 0, 0);
    }
    int orow0 = blockIdx.x * 64 + wv * 16 + quad * 4;
#pragma unroll
    for (int r = 0; r < 4; ++r) {
        int orow = orow0 + r;
        if (orow < N)
            h2s[(size_t)orow * F2 + l15] = to_bf(acc[r] * dinv[orow]);
    }
}

// ---------- Gather 2 + log_softmax: 8 lanes/node, bf16x2 per lane ----------
__global__ __launch_bounds__(256) void k_gather2(const ushort_t* __restrict__ h2s,
                                                 const int* __restrict__ offsets,
                                                 const int* __restrict__ csr_src,
                                                 const float* __restrict__ dinv,
                                                 const float* __restrict__ b2,
                                                 float* __restrict__ out) {
    int idx = blockIdx.x * 256 + threadIdx.x;
    int node = idx >> 3, sub = idx & 7;
    if (node >= N) return;
    int s = offsets[node], e = offsets[node + 1];
    float ax = 0.f, ay = 0.f;
    int k = s;
    for (; k + 4 <= e; k += 4) {
        int r0 = csr_src[k], r1 = csr_src[k + 1], r2 = csr_src[k + 2], r3 = csr_src[k + 3];
        unsigned u0 = ((const unsigned*)(h2s + (size_t)r0 * F2))[sub];
        unsigned u1 = ((const unsigned*)(h2s + (size_t)r1 * F2))[sub];
        unsigned u2 = ((const unsigned*)(h2s + (size_t)r2 * F2))[sub];
        unsigned u3 = ((const unsigned*)(h2s + (size_t)r3 * F2))[sub];
        ax += (blo(u0) + blo(u1)) + (blo(u2) + blo(u3));
        ay += (bhi(u0) + bhi(u1)) + (bhi(u2) + bhi(u3));
    }
    for (; k < e; ++k) {
        unsigned u = ((const unsigned*)(h2s + (size_t)csr_src[k] * F2))[sub];
        ax += blo(u);
        ay += bhi(u);
    }
    unsigned us = ((const unsigned*)(h2s + (size_t)node * F2))[sub];
    ax += blo(us);
    ay += bhi(us);
    float dc = dinv[node];
    float2 bb = ((const float2*)b2)[sub];
    float v0 = fmaf(dc, ax, bb.x);
    float v1 = fmaf(dc, ay, bb.y);
    // 8-lane (16-value) log-softmax; xor masks 1,2,4 stay inside the 8-lane group
    float mx = fmaxf(v0, v1);
#pragma unroll
    for (int m = 1; m < 8; m <<= 1) mx = fmaxf(mx, __shfl_xor(mx, m));
    float sm = expf(v0 - mx) + expf(v1 - mx);
#pragma unroll
    for (int m = 1; m < 8; m <<= 1) sm += __shfl_xor(sm, m);
    float lse = mx + logf(sm);
    float2 o;
    o.x = v0 - lse;
    o.y = v1 - lse;
    ((float2*)(out + (size_t)node * F2))[sub] = o;
}

extern "C" void kernel_launch(void* const* d_in, const int* in_sizes, int n_in,
                              void* d_out, int out_size, void* d_ws, size_t ws_size,
                              hipStream_t stream) {
    const float* x  = (const float*)d_in[0];
    const int*   ei = (const int*)d_in[1];
    const float* W1 = (const float*)d_in[2];
    const float* b1 = (const float*)d_in[3];
    const float* W2 = (const float*)d_in[4];
    const float* b2 = (const float*)d_in[5];
    const int* row = ei;
    const int* col = ei + E;

    char* ws = (char*)d_ws;
    int*      counts  = (int*)ws;      ws += (size_t)N * 4;
    int*      cursor  = (int*)ws;      ws += (size_t)N * 4;
    int*      offsets = (int*)ws;      ws += (size_t)(N + 4) * 4;   // padded to keep 16B alignment
    int*      csr_src = (int*)ws;      ws += (size_t)E * 4;
    float*    dinv    = (float*)ws;    ws += (size_t)N * 4;
    ushort_t* W1t     = (ushort_t*)ws; ws += (size_t)F1 * F1 * 2;
    ushort_t* W2t     = (ushort_t*)ws; ws += (size_t)F2 * F1 * 2;
    ushort_t* h1s     = (ushort_t*)ws; ws += (size_t)N * F1 * 2;
    ushort_t* h1rb    = (ushort_t*)ws; ws += (size_t)N * F1 * 2;
    ushort_t* h2s     = (ushort_t*)ws; ws += (size_t)N * F2 * 2;

    hipMemsetAsync(counts, 0, (size_t)N * 2 * 4, stream);  // counts + cursor

    k_count<<<(E + 255) / 256, 256, 0, stream>>>(col, counts);
    k_dinv<<<(N + 255) / 256, 256, 0, stream>>>(counts, dinv);
    k_scan<<<1, 1024, 0, stream>>>(counts, offsets);
    k_bucket<<<(E + 255) / 256, 256, 0, stream>>>(row, col, offsets, cursor, csr_src);

    k_prep_w<<<(F1 * F1 + 255) / 256, 256, 0, stream>>>(W1, W2, W1t, W2t);
    k_gemm1_mfma<<<(N + 63) / 64, 256, 0, stream>>>(x, W1t, dinv, h1s);
    k_gather1<<<((size_t)N * 64 + 255) / 256, 256, 0, stream>>>(h1s, offsets, csr_src, dinv, b1, h1rb);

    k_gemm2_mfma<<<(N + 63) / 64, 256, 0, stream>>>(h1rb, W2t, dinv, h2s);
    k_gather2<<<((size_t)N * 8 + 255) / 256, 256, 0, stream>>>(h2s, offsets, csr_src, dinv, b2,
                                                               (float*)d_out);
}

// Round 5
// 243.158 us; speedup vs baseline: 7.2529x; 1.1165x over previous
//
#include <hip/hip_runtime.h>
#include <math.h>

constexpr int N  = 50000;
constexpr int E  = 800000;
constexpr int F1 = 128;
constexpr int F2 = 16;

typedef unsigned short ushort_t;
typedef __bf16 bf16x8 __attribute__((ext_vector_type(8)));
typedef float  f32x4  __attribute__((ext_vector_type(4)));

static __device__ __forceinline__ float blo(unsigned u) { return __uint_as_float(u << 16); }
static __device__ __forceinline__ float bhi(unsigned u) { return __uint_as_float(u & 0xffff0000u); }
static __device__ __forceinline__ ushort_t to_bf(float f) { __bf16 h = (__bf16)f; return *(ushort_t*)&h; }

// ---------- CSR build ----------
__global__ void k_count(const int* __restrict__ col, int* __restrict__ counts) {
    int e = blockIdx.x * 256 + threadIdx.x;
    if (e < E) atomicAdd(counts + col[e], 1);
}

// dinv + unordered segment allocation (replaces the single-block scan):
// wave prefix-sum of counts, one atomicAdd per wave for the base.
__global__ void k_node_prep(const int* __restrict__ counts, float* __restrict__ dinv,
                            int* __restrict__ seg_start, int* __restrict__ gcounter) {
    int i = blockIdx.x * 256 + threadIdx.x;
    int lane = threadIdx.x & 63;
    int v = (i < N) ? counts[i] : 0;
    if (i < N) dinv[i] = rsqrtf((float)v + 1.0f);
    int incl = v;
#pragma unroll
    for (int d = 1; d < 64; d <<= 1) {
        int u = __shfl_up(incl, d, 64);
        if (lane >= d) incl += u;
    }
    int base = 0;
    if (lane == 63) base = atomicAdd(gcounter, incl);  // wave total
    base = __shfl(base, 63);
    if (i < N) seg_start[i] = base + incl - v;
}

__global__ void k_bucket(const int* __restrict__ row, const int* __restrict__ col,
                         const int* __restrict__ seg_start, int* __restrict__ cursor,
                         int* __restrict__ csr_src) {
    int e = blockIdx.x * 256 + threadIdx.x;
    if (e >= E) return;
    int c = col[e];
    int pos = atomicAdd(cursor + c, 1);
    csr_src[seg_start[c] + pos] = row[e];
}

// ---------- W1,W2 -> bf16 transposed ----------
__global__ void k_prep_w(const float* __restrict__ W1, const float* __restrict__ W2,
                         ushort_t* __restrict__ W1t, ushort_t* __restrict__ W2t) {
    int i = blockIdx.x * 256 + threadIdx.x;
    if (i < F1 * F1) {
        int k = i >> 7, n = i & 127;
        W1t[n * F1 + k] = to_bf(W1[i]);
    }
    if (i < F1 * F2) {
        int k = i >> 4, n = i & 15;
        W2t[n * F1 + k] = to_bf(W2[i]);
    }
}

// ---------- GEMM1 (MFMA bf16): h1s = bf16(dinv[r] * (x @ W1)[r]) ----------
__global__ __launch_bounds__(256) void k_gemm1_mfma(const float* __restrict__ x,
                                                    const ushort_t* __restrict__ W1t,
                                                    const float* __restrict__ dinv,
                                                    ushort_t* __restrict__ h1s) {
    __shared__ ushort_t Wl[F1 * 136];
    int t = threadIdx.x;
    for (int i = t; i < F1 * 16; i += 256) {
        int n = i >> 4, c = (i & 15) * 8;
        *(int4*)&Wl[n * 136 + c] = *(const int4*)&W1t[n * F1 + c];
    }
    __syncthreads();

    int lane = t & 63, wv = t >> 6;
    int quad = lane >> 4, l15 = lane & 15;
    int arow = blockIdx.x * 64 + wv * 16 + l15;
    int rclamp = min(arow, N - 1);
    f32x4 acc[8] = {};

#pragma unroll
    for (int kk = 0; kk < 4; ++kk) {
        int k0 = kk * 32 + quad * 8;
        const float* xp = x + (size_t)rclamp * F1 + k0;
        float4 u0 = *(const float4*)xp;
        float4 u1 = *(const float4*)(xp + 4);
        bf16x8 a;
        a[0] = (__bf16)u0.x; a[1] = (__bf16)u0.y; a[2] = (__bf16)u0.z; a[3] = (__bf16)u0.w;
        a[4] = (__bf16)u1.x; a[5] = (__bf16)u1.y; a[6] = (__bf16)u1.z; a[7] = (__bf16)u1.w;
#pragma unroll
        for (int ct = 0; ct < 8; ++ct) {
            bf16x8 b = *(const bf16x8*)&Wl[(ct * 16 + l15) * 136 + k0];
            acc[ct] = __builtin_amdgcn_mfma_f32_16x16x32_bf16(a, b, acc[ct], 0, 0, 0);
        }
    }

    int orow0 = blockIdx.x * 64 + wv * 16 + quad * 4;
#pragma unroll
    for (int r = 0; r < 4; ++r) {
        int orow = orow0 + r;
        if (orow < N) {
            float d = dinv[orow];
#pragma unroll
            for (int ct = 0; ct < 8; ++ct)
                h1s[(size_t)orow * F1 + ct * 16 + l15] = to_bf(acc[ct][r] * d);
        }
    }
}

// ---------- Gather 1: h1r = relu(dinv_c * (sum h1s[r] + h1s[c]) + b1), bf16 out ----------
__global__ __launch_bounds__(256) void k_gather1(const ushort_t* __restrict__ h1s,
                                                 const int* __restrict__ seg_start,
                                                 const int* __restrict__ counts,
                                                 const int* __restrict__ csr_src,
                                                 const float* __restrict__ dinv,
                                                 const float* __restrict__ b1,
                                                 ushort_t* __restrict__ h1rb) {
    int c = (blockIdx.x * 256 + threadIdx.x) >> 6;
    int lane = threadIdx.x & 63;
    if (c >= N) return;
    int s = seg_start[c], e = s + counts[c];
    float ax = 0.f, ay = 0.f;
    int k = s;
    for (; k + 4 <= e; k += 4) {
        int r0 = csr_src[k], r1 = csr_src[k + 1], r2 = csr_src[k + 2], r3 = csr_src[k + 3];
        unsigned u0 = ((const unsigned*)(h1s + (size_t)r0 * F1))[lane];
        unsigned u1 = ((const unsigned*)(h1s + (size_t)r1 * F1))[lane];
        unsigned u2 = ((const unsigned*)(h1s + (size_t)r2 * F1))[lane];
        unsigned u3 = ((const unsigned*)(h1s + (size_t)r3 * F1))[lane];
        ax += (blo(u0) + blo(u1)) + (blo(u2) + blo(u3));
        ay += (bhi(u0) + bhi(u1)) + (bhi(u2) + bhi(u3));
    }
    for (; k < e; ++k) {
        unsigned u = ((const unsigned*)(h1s + (size_t)csr_src[k] * F1))[lane];
        ax += blo(u);
        ay += bhi(u);
    }
    unsigned us = ((const unsigned*)(h1s + (size_t)c * F1))[lane];
    ax += blo(us);
    ay += bhi(us);
    float dc = dinv[c];
    float2 bb = ((const float2*)b1)[lane];
    float o0 = fmaxf(fmaf(dc, ax, bb.x), 0.f);
    float o1 = fmaxf(fmaf(dc, ay, bb.y), 0.f);
    unsigned pw = (unsigned)to_bf(o0) | ((unsigned)to_bf(o1) << 16);
    ((unsigned*)(h1rb + (size_t)c * F1))[lane] = pw;
}

// ---------- GEMM2 (MFMA bf16): h2s = bf16(dinv[r] * (h1r @ W2)[r]) ----------
__global__ __launch_bounds__(256) void k_gemm2_mfma(const ushort_t* __restrict__ h1rb,
                                                    const ushort_t* __restrict__ W2t,
                                                    const float* __restrict__ dinv,
                                                    ushort_t* __restrict__ h2s) {
    int t = threadIdx.x, lane = t & 63, wv = t >> 6;
    int quad = lane >> 4, l15 = lane & 15;
    int arow = blockIdx.x * 64 + wv * 16 + l15;
    int rclamp = min(arow, N - 1);
    f32x4 acc = {};
#pragma unroll
    for (int kk = 0; kk < 4; ++kk) {
        int k0 = kk * 32 + quad * 8;
        bf16x8 a = *(const bf16x8*)(h1rb + (size_t)rclamp * F1 + k0);
        bf16x8 b = *(const bf16x8*)(W2t + l15 * F1 + k0);
        acc = __builtin_amdgcn_mfma_f32_16x16x32_bf16(a, b, acc, 0, 0, 0);
    }
    int orow0 = blockIdx.x * 64 + wv * 16 + quad * 4;
#pragma unroll
    for (int r = 0; r < 4; ++r) {
        int orow = orow0 + r;
        if (orow < N)
            h2s[(size_t)orow * F2 + l15] = to_bf(acc[r] * dinv[orow]);
    }
}

// ---------- Gather 2 + log_softmax: 8 lanes/node ----------
__global__ __launch_bounds__(256) void k_gather2(const ushort_t* __restrict__ h2s,
                                                 const int* __restrict__ seg_start,
                                                 const int* __restrict__ counts,
                                                 const int* __restrict__ csr_src,
                                                 const float* __restrict__ dinv,
                                                 const float* __restrict__ b2,
                                                 float* __restrict__ out) {
    int idx = blockIdx.x * 256 + threadIdx.x;
    int node = idx >> 3, sub = idx & 7;
    if (node >= N) return;
    int s = seg_start[node], e = s + counts[node];
    float ax = 0.f, ay = 0.f;
    int k = s;
    for (; k + 4 <= e; k += 4) {
        int r0 = csr_src[k], r1 = csr_src[k + 1], r2 = csr_src[k + 2], r3 = csr_src[k + 3];
        unsigned u0 = ((const unsigned*)(h2s + (size_t)r0 * F2))[sub];
        unsigned u1 = ((const unsigned*)(h2s + (size_t)r1 * F2))[sub];
        unsigned u2 = ((const unsigned*)(h2s + (size_t)r2 * F2))[sub];
        unsigned u3 = ((const unsigned*)(h2s + (size_t)r3 * F2))[sub];
        ax += (blo(u0) + blo(u1)) + (blo(u2) + blo(u3));
        ay += (bhi(u0) + bhi(u1)) + (bhi(u2) + bhi(u3));
    }
    for (; k < e; ++k) {
        unsigned u = ((const unsigned*)(h2s + (size_t)csr_src[k] * F2))[sub];
        ax += blo(u);
        ay += bhi(u);
    }
    unsigned us = ((const unsigned*)(h2s + (size_t)node * F2))[sub];
    ax += blo(us);
    ay += bhi(us);
    float dc = dinv[node];
    float2 bb = ((const float2*)b2)[sub];
    float v0 = fmaf(dc, ax, bb.x);
    float v1 = fmaf(dc, ay, bb.y);
    float mx = fmaxf(v0, v1);
#pragma unroll
    for (int m = 1; m < 8; m <<= 1) mx = fmaxf(mx, __shfl_xor(mx, m));
    float sm = expf(v0 - mx) + expf(v1 - mx);
#pragma unroll
    for (int m = 1; m < 8; m <<= 1) sm += __shfl_xor(sm, m);
    float lse = mx + logf(sm);
    float2 o;
    o.x = v0 - lse;
    o.y = v1 - lse;
    ((float2*)(out + (size_t)node * F2))[sub] = o;
}

extern "C" void kernel_launch(void* const* d_in, const int* in_sizes, int n_in,
                              void* d_out, int out_size, void* d_ws, size_t ws_size,
                              hipStream_t stream) {
    const float* x  = (const float*)d_in[0];
    const int*   ei = (const int*)d_in[1];
    const float* W1 = (const float*)d_in[2];
    const float* b1 = (const float*)d_in[3];
    const float* W2 = (const float*)d_in[4];
    const float* b2 = (const float*)d_in[5];
    const int* row = ei;
    const int* col = ei + E;

    char* ws = (char*)d_ws;
    int*      counts    = (int*)ws;      ws += (size_t)N * 4;
    int*      cursor    = (int*)ws;      ws += (size_t)N * 4;
    int*      gcounter  = (int*)ws;      ws += 4 * 4;              // +pad for alignment
    int*      seg_start = (int*)ws;      ws += (size_t)N * 4;
    int*      csr_src   = (int*)ws;      ws += (size_t)E * 4;
    float*    dinv      = (float*)ws;    ws += (size_t)N * 4;
    ushort_t* W1t       = (ushort_t*)ws; ws += (size_t)F1 * F1 * 2;
    ushort_t* W2t       = (ushort_t*)ws; ws += (size_t)F2 * F1 * 2;
    ushort_t* h1s       = (ushort_t*)ws; ws += (size_t)N * F1 * 2;
    ushort_t* h1rb      = (ushort_t*)ws; ws += (size_t)N * F1 * 2;
    ushort_t* h2s       = (ushort_t*)ws; ws += (size_t)N * F2 * 2;

    // zero counts + cursor + gcounter (contiguous)
    hipMemsetAsync(counts, 0, ((size_t)N * 2 + 4) * 4, stream);

    k_count<<<(E + 255) / 256, 256, 0, stream>>>(col, counts);
    k_node_prep<<<(N + 255) / 256, 256, 0, stream>>>(counts, dinv, seg_start, gcounter);
    k_bucket<<<(E + 255) / 256, 256, 0, stream>>>(row, col, seg_start, cursor, csr_src);

    k_prep_w<<<(F1 * F1 + 255) / 256, 256, 0, stream>>>(W1, W2, W1t, W2t);
    k_gemm1_mfma<<<(N + 63) / 64, 256, 0, stream>>>(x, W1t, dinv, h1s);
    k_gather1<<<((size_t)N * 64 + 255) / 256, 256, 0, stream>>>(h1s, seg_start, counts, csr_src,
                                                                dinv, b1, h1rb);

    k_gemm2_mfma<<<(N + 63) / 64, 256, 0, stream>>>(h1rb, W2t, dinv, h2s);
    k_gather2<<<((size_t)N * 8 + 255) / 256, 256, 0, stream>>>(h2s, seg_start, counts, csr_src,
                                                               dinv, b2, (float*)d_out);
}

// Round 6
// 196.439 us; speedup vs baseline: 8.9779x; 1.2378x over previous
//
#include <hip/hip_runtime.h>
#include <math.h>

constexpr int N  = 50000;
constexpr int E  = 800000;
constexpr int F1 = 128;
constexpr int F2 = 16;
constexpr int NBUCKET = (N + 1023) >> 10;  // 49 coarse buckets of 1024 nodes
constexpr int CHUNK   = 4096;              // edges per block in bin kernels

typedef unsigned short ushort_t;
typedef __bf16 bf16x8 __attribute__((ext_vector_type(8)));
typedef float  f32x4  __attribute__((ext_vector_type(4)));

static __device__ __forceinline__ float blo(unsigned u) { return __uint_as_float(u << 16); }
static __device__ __forceinline__ float bhi(unsigned u) { return __uint_as_float(u & 0xffff0000u); }
static __device__ __forceinline__ ushort_t to_bf(float f) { __bf16 h = (__bf16)f; return *(ushort_t*)&h; }

// ---------- CSR build, two-level ----------
__global__ __launch_bounds__(256) void k_binCount(const int* __restrict__ col,
                                                  int* __restrict__ bucket_count) {
    __shared__ int hist[NBUCKET];
    int t = threadIdx.x;
    if (t < NBUCKET) hist[t] = 0;
    __syncthreads();
    int base = blockIdx.x * CHUNK;
#pragma unroll
    for (int i = 0; i < CHUNK / 256; ++i) {
        int e = base + i * 256 + t;
        if (e < E) atomicAdd(&hist[col[e] >> 10], 1);
    }
    __syncthreads();
    if (t < NBUCKET && hist[t]) atomicAdd(&bucket_count[t], hist[t]);
}

__global__ void k_binScan(const int* __restrict__ bucket_count,
                          int* __restrict__ bucket_start,
                          int* __restrict__ bucket_cursor) {
    int lane = threadIdx.x;  // 64 threads, single wave
    int v = (lane < NBUCKET) ? bucket_count[lane] : 0;
    int incl = v;
#pragma unroll
    for (int d = 1; d < 64; d <<= 1) {
        int u = __shfl_up(incl, d, 64);
        if (lane >= d) incl += u;
    }
    if (lane < NBUCKET) {
        bucket_start[lane]  = incl - v;
        bucket_cursor[lane] = incl - v;
    }
    if (lane == NBUCKET - 1) bucket_start[NBUCKET] = incl;  // == E
}

// scatter edges into coarse buckets as packed words: row<<10 | (col & 1023)
__global__ __launch_bounds__(256) void k_binScatter(const int* __restrict__ row,
                                                    const int* __restrict__ col,
                                                    int* __restrict__ bucket_cursor,
                                                    unsigned* __restrict__ P) {
    __shared__ int hist[NBUCKET];
    __shared__ int cur[NBUCKET];
    int t = threadIdx.x;
    if (t < NBUCKET) hist[t] = 0;
    __syncthreads();
    int base = blockIdx.x * CHUNK;
#pragma unroll
    for (int i = 0; i < CHUNK / 256; ++i) {
        int e = base + i * 256 + t;
        if (e < E) atomicAdd(&hist[col[e] >> 10], 1);
    }
    __syncthreads();
    if (t < NBUCKET) cur[t] = atomicAdd(&bucket_cursor[t], hist[t]);
    __syncthreads();
#pragma unroll
    for (int i = 0; i < CHUNK / 256; ++i) {
        int e = base + i * 256 + t;
        if (e < E) {
            int c = col[e];
            int pos = atomicAdd(&cur[c >> 10], 1);
            P[pos] = ((unsigned)row[e] << 10) | (unsigned)(c & 1023);
        }
    }
}

// per bucket: node counts + local scan -> seg_start/counts/dinv, then csr fill (ushort)
__global__ __launch_bounds__(512) void k_binFinal(const unsigned* __restrict__ P,
                                                  const int* __restrict__ bucket_start,
                                                  ushort_t* __restrict__ csr16,
                                                  int* __restrict__ seg_start,
                                                  int* __restrict__ counts,
                                                  float* __restrict__ dinv) {
    __shared__ int cnt[1024];
    __shared__ int cur[1024];
    __shared__ int wtot[8];
    int t = threadIdx.x, lane = t & 63, wid = t >> 6;
    int b = blockIdx.x;
    int lo = b << 10;
    int n_nodes = min(1024, N - lo);
    cnt[t] = 0; cnt[t + 512] = 0;
    __syncthreads();
    int s = bucket_start[b], e = bucket_start[b + 1];
    for (int k = s + t; k < e; k += 512)
        atomicAdd(&cnt[P[k] & 1023], 1);
    __syncthreads();
    int v0 = cnt[2 * t], v1 = cnt[2 * t + 1];
    int p = v0 + v1;
    int incl = p;
#pragma unroll
    for (int d = 1; d < 64; d <<= 1) {
        int u = __shfl_up(incl, d, 64);
        if (lane >= d) incl += u;
    }
    if (lane == 63) wtot[wid] = incl;
    __syncthreads();
    int wb = 0;
    for (int w = 0; w < wid; ++w) wb += wtot[w];
    int excl = wb + incl - p;
    int o0 = s + excl, o1 = s + excl + v0;
    cur[2 * t] = o0; cur[2 * t + 1] = o1;
    int i0 = 2 * t, i1 = 2 * t + 1;
    if (i0 < n_nodes) {
        seg_start[lo + i0] = o0; counts[lo + i0] = v0;
        dinv[lo + i0] = rsqrtf((float)v0 + 1.f);
    }
    if (i1 < n_nodes) {
        seg_start[lo + i1] = o1; counts[lo + i1] = v1;
        dinv[lo + i1] = rsqrtf((float)v1 + 1.f);
    }
    __syncthreads();
    for (int k = s + t; k < e; k += 512) {
        unsigned u = P[k];
        int pos = atomicAdd(&cur[u & 1023], 1);
        csr16[pos] = (ushort_t)(u >> 10);
    }
}

// ---------- W1,W2 -> bf16 transposed ----------
__global__ void k_prep_w(const float* __restrict__ W1, const float* __restrict__ W2,
                         ushort_t* __restrict__ W1t, ushort_t* __restrict__ W2t) {
    int i = blockIdx.x * 256 + threadIdx.x;
    if (i < F1 * F1) {
        int k = i >> 7, n = i & 127;
        W1t[n * F1 + k] = to_bf(W1[i]);
    }
    if (i < F1 * F2) {
        int k = i >> 4, n = i & 15;
        W2t[n * F1 + k] = to_bf(W2[i]);
    }
}

// ---------- GEMM1 (MFMA bf16): h1s = bf16(dinv[r] * (x @ W1)[r]) ----------
__global__ __launch_bounds__(256) void k_gemm1_mfma(const float* __restrict__ x,
                                                    const ushort_t* __restrict__ W1t,
                                                    const float* __restrict__ dinv,
                                                    ushort_t* __restrict__ h1s) {
    __shared__ ushort_t Wl[F1 * 136];
    int t = threadIdx.x;
    for (int i = t; i < F1 * 16; i += 256) {
        int n = i >> 4, c = (i & 15) * 8;
        *(int4*)&Wl[n * 136 + c] = *(const int4*)&W1t[n * F1 + c];
    }
    __syncthreads();

    int lane = t & 63, wv = t >> 6;
    int quad = lane >> 4, l15 = lane & 15;
    int arow = blockIdx.x * 64 + wv * 16 + l15;
    int rclamp = min(arow, N - 1);
    f32x4 acc[8] = {};

#pragma unroll
    for (int kk = 0; kk < 4; ++kk) {
        int k0 = kk * 32 + quad * 8;
        const float* xp = x + (size_t)rclamp * F1 + k0;
        float4 u0 = *(const float4*)xp;
        float4 u1 = *(const float4*)(xp + 4);
        bf16x8 a;
        a[0] = (__bf16)u0.x; a[1] = (__bf16)u0.y; a[2] = (__bf16)u0.z; a[3] = (__bf16)u0.w;
        a[4] = (__bf16)u1.x; a[5] = (__bf16)u1.y; a[6] = (__bf16)u1.z; a[7] = (__bf16)u1.w;
#pragma unroll
        for (int ct = 0; ct < 8; ++ct) {
            bf16x8 b = *(const bf16x8*)&Wl[(ct * 16 + l15) * 136 + k0];
            acc[ct] = __builtin_amdgcn_mfma_f32_16x16x32_bf16(a, b, acc[ct], 0, 0, 0);
        }
    }

    int orow0 = blockIdx.x * 64 + wv * 16 + quad * 4;
#pragma unroll
    for (int r = 0; r < 4; ++r) {
        int orow = orow0 + r;
        if (orow < N) {
            float d = dinv[orow];
#pragma unroll
            for (int ct = 0; ct < 8; ++ct)
                h1s[(size_t)orow * F1 + ct * 16 + l15] = to_bf(acc[ct][r] * d);
        }
    }
}

// ---------- Gather 1: h1r = relu(dinv_c * (sum h1s[r] + h1s[c]) + b1), bf16 out ----------
__global__ __launch_bounds__(256) void k_gather1(const ushort_t* __restrict__ h1s,
                                                 const int* __restrict__ seg_start,
                                                 const int* __restrict__ counts,
                                                 const ushort_t* __restrict__ csr16,
                                                 const float* __restrict__ dinv,
                                                 const float* __restrict__ b1,
                                                 ushort_t* __restrict__ h1rb) {
    int c = (blockIdx.x * 256 + threadIdx.x) >> 6;
    int lane = threadIdx.x & 63;
    if (c >= N) return;
    int s = seg_start[c], e = s + counts[c];
    float ax = 0.f, ay = 0.f;
    int k = s;
    for (; k + 4 <= e; k += 4) {
        int r0 = csr16[k], r1 = csr16[k + 1], r2 = csr16[k + 2], r3 = csr16[k + 3];
        unsigned u0 = ((const unsigned*)(h1s + (size_t)r0 * F1))[lane];
        unsigned u1 = ((const unsigned*)(h1s + (size_t)r1 * F1))[lane];
        unsigned u2 = ((const unsigned*)(h1s + (size_t)r2 * F1))[lane];
        unsigned u3 = ((const unsigned*)(h1s + (size_t)r3 * F1))[lane];
        ax += (blo(u0) + blo(u1)) + (blo(u2) + blo(u3));
        ay += (bhi(u0) + bhi(u1)) + (bhi(u2) + bhi(u3));
    }
    for (; k < e; ++k) {
        unsigned u = ((const unsigned*)(h1s + (size_t)csr16[k] * F1))[lane];
        ax += blo(u);
        ay += bhi(u);
    }
    unsigned us = ((const unsigned*)(h1s + (size_t)c * F1))[lane];
    ax += blo(us);
    ay += bhi(us);
    float dc = dinv[c];
    float2 bb = ((const float2*)b1)[lane];
    float o0 = fmaxf(fmaf(dc, ax, bb.x), 0.f);
    float o1 = fmaxf(fmaf(dc, ay, bb.y), 0.f);
    unsigned pw = (unsigned)to_bf(o0) | ((unsigned)to_bf(o1) << 16);
    ((unsigned*)(h1rb + (size_t)c * F1))[lane] = pw;
}

// ---------- GEMM2 (MFMA bf16): h2s = bf16(dinv[r] * (h1r @ W2)[r]) ----------
__global__ __launch_bounds__(256) void k_gemm2_mfma(const ushort_t* __restrict__ h1rb,
                                                    const ushort_t* __restrict__ W2t,
                                                    const float* __restrict__ dinv,
                                                    ushort_t* __restrict__ h2s) {
    int t = threadIdx.x, lane = t & 63, wv = t >> 6;
    int quad = lane >> 4, l15 = lane & 15;
    int arow = blockIdx.x * 64 + wv * 16 + l15;
    int rclamp = min(arow, N - 1);
    f32x4 acc = {};
#pragma unroll
    for (int kk = 0; kk < 4; ++kk) {
        int k0 = kk * 32 + quad * 8;
        bf16x8 a = *(const bf16x8*)(h1rb + (size_t)rclamp * F1 + k0);
        bf16x8 b = *(const bf16x8*)(W2t + l15 * F1 + k0);
        acc = __builtin_amdgcn_mfma_f32_16x16x32_bf16(a, b, acc, 0, 0, 0);
    }
    int orow0 = blockIdx.x * 64 + wv * 16 + quad * 4;
#pragma unroll
    for (int r = 0; r < 4; ++r) {
        int orow = orow0 + r;
        if (orow < N)
            h2s[(size_t)orow * F2 + l15] = to_bf(acc[r] * dinv[orow]);
    }
}

// ---------- Gather 2 + log_softmax: 8 lanes/node ----------
__global__ __launch_bounds__(256) void k_gather2(const ushort_t* __restrict__ h2s,
                                                 const int* __restrict__ seg_start,
                                                 const int* __restrict__ counts,
                                                 const ushort_t* __restrict__ csr16,
                                                 const float* __restrict__ dinv,
                                                 const float* __restrict__ b2,
                                                 float* __restrict__ out) {
    int idx = blockIdx.x * 256 + threadIdx.x;
    int node = idx >> 3, sub = idx & 7;
    if (node >= N) return;
    int s = seg_start[node], e = s + counts[node];
    float ax = 0.f, ay = 0.f;
    int k = s;
    for (; k + 4 <= e; k += 4) {
        int r0 = csr16[k], r1 = csr16[k + 1], r2 = csr16[k + 2], r3 = csr16[k + 3];
        unsigned u0 = ((const unsigned*)(h2s + (size_t)r0 * F2))[sub];
        unsigned u1 = ((const unsigned*)(h2s + (size_t)r1 * F2))[sub];
        unsigned u2 = ((const unsigned*)(h2s + (size_t)r2 * F2))[sub];
        unsigned u3 = ((const unsigned*)(h2s + (size_t)r3 * F2))[sub];
        ax += (blo(u0) + blo(u1)) + (blo(u2) + blo(u3));
        ay += (bhi(u0) + bhi(u1)) + (bhi(u2) + bhi(u3));
    }
    for (; k < e; ++k) {
        unsigned u = ((const unsigned*)(h2s + (size_t)csr16[k] * F2))[sub];
        ax += blo(u);
        ay += bhi(u);
    }
    unsigned us = ((const unsigned*)(h2s + (size_t)node * F2))[sub];
    ax += blo(us);
    ay += bhi(us);
    float dc = dinv[node];
    float2 bb = ((const float2*)b2)[sub];
    float v0 = fmaf(dc, ax, bb.x);
    float v1 = fmaf(dc, ay, bb.y);
    float mx = fmaxf(v0, v1);
#pragma unroll
    for (int m = 1; m < 8; m <<= 1) mx = fmaxf(mx, __shfl_xor(mx, m));
    float sm = expf(v0 - mx) + expf(v1 - mx);
#pragma unroll
    for (int m = 1; m < 8; m <<= 1) sm += __shfl_xor(sm, m);
    float lse = mx + logf(sm);
    float2 o;
    o.x = v0 - lse;
    o.y = v1 - lse;
    ((float2*)(out + (size_t)node * F2))[sub] = o;
}

extern "C" void kernel_launch(void* const* d_in, const int* in_sizes, int n_in,
                              void* d_out, int out_size, void* d_ws, size_t ws_size,
                              hipStream_t stream) {
    const float* x  = (const float*)d_in[0];
    const int*   ei = (const int*)d_in[1];
    const float* W1 = (const float*)d_in[2];
    const float* b1 = (const float*)d_in[3];
    const float* W2 = (const float*)d_in[4];
    const float* b2 = (const float*)d_in[5];
    const int* row = ei;
    const int* col = ei + E;

    char* ws = (char*)d_ws;
    int*      bucket_count  = (int*)ws;  ws += 64 * 4;
    int*      bucket_start  = (int*)ws;  ws += 64 * 4;
    int*      bucket_cursor = (int*)ws;  ws += 64 * 4;
    unsigned* P             = (unsigned*)ws; ws += (size_t)E * 4;
    ushort_t* csr16         = (ushort_t*)ws; ws += (size_t)(E + 8) * 2;
    int*      seg_start     = (int*)ws;  ws += (size_t)N * 4;
    int*      counts        = (int*)ws;  ws += (size_t)N * 4;
    float*    dinv          = (float*)ws; ws += (size_t)N * 4;
    ushort_t* W1t           = (ushort_t*)ws; ws += (size_t)F1 * F1 * 2;
    ushort_t* W2t           = (ushort_t*)ws; ws += (size_t)F2 * F1 * 2;
    ushort_t* h1s           = (ushort_t*)ws; ws += (size_t)N * F1 * 2;
    ushort_t* h1rb          = (ushort_t*)ws; ws += (size_t)N * F1 * 2;
    ushort_t* h2s           = (ushort_t*)ws; ws += (size_t)N * F2 * 2;

    hipMemsetAsync(bucket_count, 0, 64 * 4, stream);

    int nbin_blocks = (E + CHUNK - 1) / CHUNK;
    k_binCount<<<nbin_blocks, 256, 0, stream>>>(col, bucket_count);
    k_binScan<<<1, 64, 0, stream>>>(bucket_count, bucket_start, bucket_cursor);
    k_binScatter<<<nbin_blocks, 256, 0, stream>>>(row, col, bucket_cursor, P);
    k_binFinal<<<NBUCKET, 512, 0, stream>>>(P, bucket_start, csr16, seg_start, counts, dinv);

    k_prep_w<<<(F1 * F1 + 255) / 256, 256, 0, stream>>>(W1, W2, W1t, W2t);
    k_gemm1_mfma<<<(N + 63) / 64, 256, 0, stream>>>(x, W1t, dinv, h1s);
    k_gather1<<<((size_t)N * 64 + 255) / 256, 256, 0, stream>>>(h1s, seg_start, counts, csr16,
                                                                dinv, b1, h1rb);

    k_gemm2_mfma<<<(N + 63) / 64, 256, 0, stream>>>(h1rb, W2t, dinv, h2s);
    k_gather2<<<((size_t)N * 8 + 255) / 256, 256, 0, stream>>>(h2s, seg_start, counts, csr16,
                                                               dinv, b2, (float*)d_out);
}